// Round 11
// baseline (170.101 us; speedup 1.0000x reference)
//
#include <hip/hip_runtime.h>
#include <math.h>

#define H 64
#define NXCD 8

typedef __attribute__((ext_vector_type(8))) short short8;
typedef __attribute__((ext_vector_type(4))) float f32x4;
typedef __attribute__((ext_vector_type(4))) int i32x4;

__device__ inline ushort f2bf(float f) {
    union { float f; unsigned u; } v;
    v.f = f;
    unsigned r = v.u + 0x7FFFu + ((v.u >> 16) & 1u);
    return (ushort)(r >> 16);
}

// ---------- Pass 1: histogram of destinations (int4-vectorized nt reads) ----------
__global__ void k_hist(const int* __restrict__ dst, unsigned* __restrict__ cnt, int E) {
    int i = blockIdx.x * blockDim.x + threadIdx.x;
    int st = gridDim.x * blockDim.x;
    int E4 = E >> 2;
    const i32x4* d4 = (const i32x4*)dst;
    for (int k = i; k < E4; k += st) {
        i32x4 v = __builtin_nontemporal_load(&d4[k]);
        atomicAdd(&cnt[v.x], 1u);
        atomicAdd(&cnt[v.y], 1u);
        atomicAdd(&cnt[v.z], 1u);
        atomicAdd(&cnt[v.w], 1u);
    }
    for (int k = (E4 << 2) + i; k < E; k += st) atomicAdd(&cnt[dst[k]], 1u);
}

// ---------- Hierarchical exclusive scan ----------
__global__ __launch_bounds__(1024) void k_scanA(const unsigned* __restrict__ cnt,
                                                unsigned* __restrict__ base,
                                                unsigned* __restrict__ bsum, int N) {
    __shared__ unsigned wsum[16];
    int i = blockIdx.x * 1024 + threadIdx.x;
    unsigned v = (i < N) ? cnt[i] : 0u;
    int lane = threadIdx.x & 63, w = threadIdx.x >> 6;
    unsigned x = v;
#pragma unroll
    for (int off = 1; off < 64; off <<= 1) {
        unsigned y = __shfl_up(x, off, 64);
        if (lane >= off) x += y;
    }
    if (lane == 63) wsum[w] = x;
    __syncthreads();
    if (threadIdx.x < 16) {
        unsigned s = wsum[threadIdx.x];
#pragma unroll
        for (int off = 1; off < 16; off <<= 1) {
            unsigned y = __shfl_up(s, off, 16);
            if ((threadIdx.x & 15) >= off) s += y;
        }
        wsum[threadIdx.x] = s;
    }
    __syncthreads();
    unsigned wbase = (w > 0) ? wsum[w - 1] : 0u;
    if (i < N) base[i] = wbase + x - v;
    if (threadIdx.x == 1023) bsum[blockIdx.x] = wsum[15];
}

__global__ __launch_bounds__(1024) void k_scanB(const unsigned* __restrict__ bsum,
                                                unsigned* __restrict__ boff, int nb) {
    __shared__ unsigned wsum[16];
    int i = threadIdx.x;
    unsigned v = (i < nb) ? bsum[i] : 0u;
    int lane = i & 63, w = i >> 6;
    unsigned x = v;
#pragma unroll
    for (int off = 1; off < 64; off <<= 1) {
        unsigned y = __shfl_up(x, off, 64);
        if (lane >= off) x += y;
    }
    if (lane == 63) wsum[w] = x;
    __syncthreads();
    if (i < 16) {
        unsigned s = wsum[i];
#pragma unroll
        for (int off = 1; off < 16; off <<= 1) {
            unsigned y = __shfl_up(s, off, 16);
            if ((i & 15) >= off) s += y;
        }
        wsum[i] = s;
    }
    __syncthreads();
    unsigned wbase = (w > 0) ? wsum[w - 1] : 0u;
    if (i < nb) boff[i] = wbase + x - v;
}

__global__ void k_scanC(unsigned* __restrict__ base, unsigned* __restrict__ cursor,
                        const unsigned* __restrict__ boff, int N, int E) {
    int i = blockIdx.x * blockDim.x + threadIdx.x;
    int st = gridDim.x * blockDim.x;
    for (; i < N; i += st) {
        unsigned b = base[i] + boff[i >> 10];
        base[i] = b;
        cursor[i] = b;
    }
    if (blockIdx.x == 0 && threadIdx.x == 0) base[N] = (unsigned)E;
}

// ---------- Pass 2 (fast path): XCD-partitioned CSR bucketing, nt streaming reads ----------
// Streaming dst/src/t reads are nontemporal so the XCD's L2 is reserved for
// assembling payload cache lines (normal cached stores) before they stream out.
__global__ void k_permute_part(const int* __restrict__ dst, const int* __restrict__ src,
                               const float* __restrict__ t, unsigned* __restrict__ cursor,
                               int2* __restrict__ payload, int E, int N) {
    const float inv = 1.0f / (0.5f + 1e-8f);
    int part = blockIdx.x & (NXCD - 1);
    int nslice = gridDim.x >> 3;
    int sblk = blockIdx.x >> 3;
    int lo = (int)((long long)part * N / NXCD);
    int hi = (int)((long long)(part + 1) * N / NXCD);
    int e0 = (int)((long long)sblk * E / nslice);
    int e1 = (int)((long long)(sblk + 1) * E / nslice);
    for (int i = e0 + threadIdx.x; i < e1; i += blockDim.x) {
        int d = __builtin_nontemporal_load(&dst[i]);
        if (d >= lo && d < hi) {
            unsigned pos = atomicAdd(&cursor[d], 1u);
            float tv = __builtin_nontemporal_load(&t[i]);
            int sv = __builtin_nontemporal_load(&src[i]);
            float e = __expf(tv * inv);
            payload[pos] = make_int2(sv, __float_as_int(e));
        }
    }
}

// ---------- Pass 2 (fallback): plain packing permute ----------
__global__ void k_permute_pack(const int* __restrict__ dst, const int* __restrict__ src,
                               const float* __restrict__ t, unsigned* __restrict__ cursor,
                               int2* __restrict__ payload, int E) {
    const float inv = 1.0f / (0.5f + 1e-8f);
    int i = blockIdx.x * blockDim.x + threadIdx.x;
    int st = gridDim.x * blockDim.x;
    for (; i < E; i += st) {
        unsigned pos = atomicAdd(&cursor[dst[i]], 1u);
        float e = __expf(t[i] * inv);
        payload[pos] = make_int2(src[i], __float_as_int(e));
    }
}

// ---------- Pre-transform: y(bf16) = x @ W^T via MFMA 16x16x32 bf16 (verified R8) ----------
__global__ __launch_bounds__(256) void k_xform_mfma(const float* __restrict__ x,
                                                    const float* __restrict__ W,
                                                    ushort* __restrict__ y, int M) {
    int wid = (blockIdx.x * blockDim.x + threadIdx.x) >> 6;
    int lane = threadIdx.x & 63;
    int n0 = wid * 16;
    if (n0 >= M) return;
    int r = lane & 15, g = lane >> 4;

    short8 bfrag[4][2];
#pragma unroll
    for (int ct = 0; ct < 4; ++ct) {
#pragma unroll
        for (int kh = 0; kh < 2; ++kh) {
            const float* wp = &W[(size_t)(ct * 16 + r) * 64 + kh * 32 + g * 8];
            float4 w0 = *(const float4*)wp;
            float4 w1 = *(const float4*)(wp + 4);
            short8 bf;
            bf[0] = (short)f2bf(w0.x); bf[1] = (short)f2bf(w0.y);
            bf[2] = (short)f2bf(w0.z); bf[3] = (short)f2bf(w0.w);
            bf[4] = (short)f2bf(w1.x); bf[5] = (short)f2bf(w1.y);
            bf[6] = (short)f2bf(w1.z); bf[7] = (short)f2bf(w1.w);
            bfrag[ct][kh] = bf;
        }
    }
    int xr = n0 + r;
    if (xr >= M) xr = M - 1;
    const float* xp = &x[(size_t)xr * 64 + g * 8];
    short8 afrag[2];
#pragma unroll
    for (int kh = 0; kh < 2; ++kh) {
        float4 a0 = *(const float4*)(xp + kh * 32);
        float4 a1 = *(const float4*)(xp + kh * 32 + 4);
        short8 af;
        af[0] = (short)f2bf(a0.x); af[1] = (short)f2bf(a0.y);
        af[2] = (short)f2bf(a0.z); af[3] = (short)f2bf(a0.w);
        af[4] = (short)f2bf(a1.x); af[5] = (short)f2bf(a1.y);
        af[6] = (short)f2bf(a1.z); af[7] = (short)f2bf(a1.w);
        afrag[kh] = af;
    }
#pragma unroll
    for (int ct = 0; ct < 4; ++ct) {
        f32x4 acc = {0.f, 0.f, 0.f, 0.f};
        acc = __builtin_amdgcn_mfma_f32_16x16x32_bf16(afrag[0], bfrag[ct][0], acc, 0, 0, 0);
        acc = __builtin_amdgcn_mfma_f32_16x16x32_bf16(afrag[1], bfrag[ct][1], acc, 0, 0, 0);
#pragma unroll
        for (int q = 0; q < 4; ++q) {
            int row = n0 + g * 4 + q;
            if (row < M) y[(size_t)row * 64 + ct * 16 + r] = f2bf(acc[q]);
        }
    }
}

// ---------- Pass 3: weighted gather, 4 dests/wave, 16 lanes/dest, no shfls (verified R10) ----------
__global__ __launch_bounds__(256) void k_gather4(const unsigned* __restrict__ base,
                                                 const long long* __restrict__ payload,
                                                 const uint2* __restrict__ y2,
                                                 float* __restrict__ out, int N) {
    int tid = blockIdx.x * blockDim.x + threadIdx.x;
    int lane = threadIdx.x & 63;
    int g = lane >> 4, f = lane & 15;
    int d = (tid >> 6) * 4 + g;
    if (d >= N) return;
    unsigned r0 = base[d], r1 = base[d + 1];
    int deg = (int)(r1 - r0);
    float acc0 = 0.f, acc1 = 0.f, acc2 = 0.f, acc3 = 0.f, ssum = 0.f;
    for (int it = 0; it < deg; it += 4) {
        float e[4];
        int s[4];
#pragma unroll
        for (int k2 = 0; k2 < 4; ++k2) {
            // memory-safe overread: payload region is followed by the y region in ws
            long long pl = __builtin_nontemporal_load(&payload[r0 + it + k2]);
            bool ok = (it + k2) < deg;
            e[k2] = ok ? __int_as_float((int)(pl >> 32)) : 0.f;
            s[k2] = ok ? (int)(pl & 0xFFFFFFFFll) : 0;
            ssum += e[k2];
        }
        uint2 v[4];
#pragma unroll
        for (int k2 = 0; k2 < 4; ++k2) v[k2] = y2[(size_t)s[k2] * 16 + f];
#pragma unroll
        for (int k2 = 0; k2 < 4; ++k2) {
            float x0 = __uint_as_float(v[k2].x << 16);
            float x1 = __uint_as_float(v[k2].x & 0xFFFF0000u);
            float x2 = __uint_as_float(v[k2].y << 16);
            float x3 = __uint_as_float(v[k2].y & 0xFFFF0000u);
            acc0 = fmaf(e[k2], x0, acc0);
            acc1 = fmaf(e[k2], x1, acc1);
            acc2 = fmaf(e[k2], x2, acc2);
            acc3 = fmaf(e[k2], x3, acc3);
        }
    }
    float rs = 1.0f / (ssum + 1e-16f);
    f32x4 o = {acc0 * rs, acc1 * rs, acc2 * rs, acc3 * rs};
    __builtin_nontemporal_store(o, (f32x4*)&out[(size_t)d * H + f * 4]);
}

// ---------- Fallback (verified R3/R5): gather x_src with fused W epilogue ----------
__global__ __launch_bounds__(256) void k_gather_fb(const unsigned* __restrict__ base,
                                                   const int2* __restrict__ payload,
                                                   const float* __restrict__ x_src,
                                                   const float* __restrict__ W,
                                                   float* __restrict__ out, int N) {
    __shared__ float wt[H * H];
    for (int idx = threadIdx.x; idx < H * H; idx += blockDim.x) {
        int j = idx >> 6, k = idx & 63;
        wt[k * H + j] = W[idx];
    }
    __syncthreads();
    int lane = threadIdx.x & 63;
    int wid = (blockIdx.x * blockDim.x + threadIdx.x) >> 6;
    int nw = (gridDim.x * blockDim.x) >> 6;
    for (int d = wid; d < N; d += nw) {
        unsigned r0 = base[d], r1 = base[d + 1];
        int deg = (int)(r1 - r0);
        float acc = 0.0f, ssum = 0.0f;
        for (int c = 0; c < deg; c += 64) {
            int j = c + lane;
            int cd = min(64, deg - c);
            float e = 0.0f;
            int sidx = 0;
            if (j < deg) {
                int2 p = payload[r0 + j];
                sidx = p.x;
                e = __int_as_float(p.y);
            }
            float cs = e;
#pragma unroll
            for (int off = 32; off >= 1; off >>= 1) cs += __shfl_xor(cs, off, 64);
            ssum += cs;
            for (int q = 0; q < cd; q += 8) {
                float a[8];
                int sv[8];
                float v[8];
#pragma unroll
                for (int u = 0; u < 8; ++u) {
                    a[u] = __shfl(e, q + u, 64);
                    sv[u] = __shfl(sidx, q + u, 64);
                }
#pragma unroll
                for (int u = 0; u < 8; ++u) v[u] = x_src[(size_t)sv[u] * H + lane];
#pragma unroll
                for (int u = 0; u < 8; ++u) acc = fmaf(a[u], v[u], acc);
            }
        }
        acc *= 1.0f / (ssum + 1e-16f);
        float o = 0.0f;
#pragma unroll
        for (int k = 0; k < H; ++k) o = fmaf(__shfl(acc, k, 64), wt[k * H + lane], o);
        out[(size_t)d * H + lane] = o;
    }
}

extern "C" void kernel_launch(void* const* d_in, const int* in_sizes, int n_in,
                              void* d_out, int out_size, void* d_ws, size_t ws_size,
                              hipStream_t stream) {
    const float* x_src = (const float*)d_in[0];
    const float* W = (const float*)d_in[2];
    const int* edge_index = (const int*)d_in[3];
    const float* t = (const float*)d_in[4];

    int E = in_sizes[4];
    int N = in_sizes[1] / H;  // N_DST
    int M = in_sizes[0] / H;  // N_SRC
    const int* src = edge_index;
    const int* dst = edge_index + E;

    // ws layout: base[N+1] | cursor[N] | bsum[1024] | boff[1024] | payload(int2,8B-aligned)[E] | y bf16 (16B-aligned)[M*H]
    unsigned* base = (unsigned*)d_ws;
    unsigned* cursor = base + (size_t)N + 1;
    unsigned* bsum = cursor + N;
    unsigned* boff = bsum + 1024;
    size_t pay_off = (((size_t)(2 * N + 2049)) * 4 + 7) & ~(size_t)7;
    int2* payload = (int2*)((char*)d_ws + pay_off);
    size_t y_off = (pay_off + (size_t)E * 8 + 15) & ~(size_t)15;
    ushort* y = (ushort*)((char*)d_ws + y_off);

    bool have_payload = (ws_size >= pay_off + (size_t)E * 8 + 32);
    bool have_y = (ws_size >= y_off + (size_t)M * H * 2);

    int nb = (N + 1023) / 1024;

    hipMemsetAsync(cursor, 0, (size_t)N * sizeof(unsigned), stream);

    int blocks_e = (E + 255) / 256;
    if (blocks_e > 2048) blocks_e = 2048;

    k_hist<<<1024, 256, 0, stream>>>(dst, cursor, E);
    k_scanA<<<nb, 1024, 0, stream>>>(cursor, base, bsum, N);
    k_scanB<<<1, 1024, 0, stream>>>(bsum, boff, nb);
    k_scanC<<<512, 256, 0, stream>>>(base, cursor, boff, N, E);

    if (have_y) {
        int xblocks = ((M + 15) / 16 * 64 + 255) / 256;
        k_xform_mfma<<<xblocks, 256, 0, stream>>>(x_src, W, y, M);
        k_permute_part<<<2048, 256, 0, stream>>>(dst, src, t, cursor, payload, E, N);
        int gblocks = (N + 15) / 16;  // 4 waves/block, 4 dests/wave
        k_gather4<<<gblocks, 256, 0, stream>>>(base, (const long long*)payload,
                                               (const uint2*)y, (float*)d_out, N);
    } else if (have_payload) {
        k_permute_pack<<<blocks_e, 256, 0, stream>>>(dst, src, t, cursor, payload, E);
        k_gather_fb<<<4096, 256, 0, stream>>>(base, payload, x_src, W, (float*)d_out, N);
    } else {
        k_permute_pack<<<blocks_e, 256, 0, stream>>>(dst, src, t, cursor, payload, E);
        k_gather_fb<<<4096, 256, 0, stream>>>(base, payload, x_src, W, (float*)d_out, N);
    }
}